// Round 1
// baseline (23663.844 us; speedup 1.0000x reference)
//
#include <hip/hip_runtime.h>
#include <stdint.h>

#define T_STEPS 512
#define NGRP 16u

typedef short short8 __attribute__((ext_vector_type(8)));
typedef float f32x4 __attribute__((ext_vector_type(4)));

// ---- ws layout (bytes) ----
#define OFF_DONE1 0                       // [512][16] counters, 64B padded = 512 KB
#define OFF_DONE2 (512 * 1024)            // [512] counters, 64B padded = 32 KB
#define OFF_HBUF0 (OFF_DONE2 + 512 * 64)  // 64*1024 bf16 = 128 KB
#define OFF_HBUF1 (OFF_HBUF0 + 64 * 1024 * 2)
#define OFF_XBF   (OFF_HBUF1 + 64 * 1024 * 2)      // = 819200; [512][64][512] bf16 = 32 MB
#define OFF_WPACK (OFF_XBF + 512 * 64 * 512 * 2)   // [4096][1536] bf16 = 12 MB
#define MEMSET_BYTES OFF_XBF

__device__ __forceinline__ unsigned short f2bf(float f) {
  unsigned u = __float_as_uint(f);
  u += 0x7fffu + ((u >> 16) & 1u);   // RNE (inputs are finite randoms)
  return (unsigned short)(u >> 16);
}

__device__ __forceinline__ void g2l16(const void* g, void* l) {
  // 16B per lane, wave-cooperative DMA global->LDS
  __builtin_amdgcn_global_load_lds(
      (const __attribute__((address_space(1))) void*)g,
      (__attribute__((address_space(3))) void*)l,
      16, 0, 0);
}

// ---- prep: x [B][T][D] f32 -> xbf [T][B][D] bf16 ----
__global__ __launch_bounds__(256) void k_xconv(const float* __restrict__ x,
                                               unsigned short* __restrict__ xbf) {
  int g = blockIdx.x * 256 + threadIdx.x;   // 2,097,152 threads, 8 elems each
  int d8 = g & 63;
  int b = (g >> 6) & 63;
  int t = g >> 12;
  const float* src = x + (((size_t)b * 512 + t) * 512 + d8 * 8);
  float4 v0 = *(const float4*)src;
  float4 v1 = *(const float4*)(src + 4);
  short8 o;
  o[0] = (short)f2bf(v0.x); o[1] = (short)f2bf(v0.y);
  o[2] = (short)f2bf(v0.z); o[3] = (short)f2bf(v0.w);
  o[4] = (short)f2bf(v1.x); o[5] = (short)f2bf(v1.y);
  o[6] = (short)f2bf(v1.z); o[7] = (short)f2bf(v1.w);
  *(short8*)(xbf + (((size_t)t * 64 + b) * 512 + d8 * 8)) = o;
}

// ---- prep: W [k][col] f32 -> Wpack [colpack][k] bf16 (B-fragment friendly) ----
// colpack = cg*64 + gate*16 + ul  for col = gate*1024 + cg*16 + ul
__global__ __launch_bounds__(256) void k_wpack(const float* __restrict__ Wx,
                                               const float* __restrict__ Wh,
                                               unsigned short* __restrict__ wp) {
  __shared__ unsigned short tile[64 * 68];
  int tid = threadIdx.x, lane = tid & 63, wave = tid >> 6;
  int kt = blockIdx.x >> 6;   // 0..23
  int ct = blockIdx.x & 63;   // 0..63
  int K0 = kt * 64, C0 = ct * 64;
  const float* src = (K0 < 512) ? (Wx + (size_t)K0 * 4096)
                                : (Wh + (size_t)(K0 - 512) * 4096);
  #pragma unroll
  for (int i = 0; i < 16; ++i) {
    int kl = i * 4 + wave;
    float v = src[(size_t)kl * 4096 + C0 + lane];
    tile[lane * 68 + kl] = f2bf(v);     // transposed store
  }
  __syncthreads();
  #pragma unroll
  for (int i = 0; i < 16; ++i) {
    int c = i * 4 + wave;
    int col = C0 + c;
    int gg = col >> 10, idx = col & 1023;
    int cp = (idx >> 4) * 64 + gg * 16 + (idx & 15);
    wp[(size_t)cp * 1536 + K0 + lane] = tile[c * 68 + lane];
  }
}

// ---- persistent scan kernel ----
// 256 blocks x 256 threads. block: mg = blockIdx&3 (16 batch rows), cg = blockIdx>>2 (16 u's).
// wave w handles gate w (16 cols), M=16 rows, K=1536. B-frags resident in VGPRs.
__global__ __launch_bounds__(256, 1) void k_scan(
    const unsigned short* __restrict__ xbf,
    const unsigned short* __restrict__ wp,
    const float* __restrict__ bias,
    float* __restrict__ out,
    unsigned* __restrict__ done1,
    unsigned* __restrict__ done2,
    unsigned short* __restrict__ hb0,
    unsigned short* __restrict__ hb1) {
  // padded strides: 520 shorts = 260 dw (%32==4 -> 2-way, free); 1032 = 516 dw (%32==4)
  __shared__ __align__(16) unsigned short Ax[16 * 520];
  __shared__ __align__(16) unsigned short Ah[16 * 1032];
  __shared__ float Gs[4 * 256];

  const int tid = threadIdx.x;
  const int lane = tid & 63;
  const int wave = tid >> 6;
  const int mg = blockIdx.x & 3;
  const int cg = blockIdx.x >> 2;
  const int grp = blockIdx.x >> 4;   // 16 groups of 16
  const int arow = lane & 15;
  const int quad = lane >> 4;

  // preload weight B-fragments for this wave's 16 cols: 48 frags = 192 VGPRs
  short8 wf[48];
  {
    const unsigned short* wbase =
        wp + (size_t)(cg * 64 + wave * 16 + arow) * 1536 + quad * 8;
    #pragma unroll
    for (int kk = 0; kk < 48; ++kk)
      wf[kk] = *(const short8*)(wbase + kk * 32);
  }
  const int u = tid & 15, m = tid >> 4;
  const int ug = cg * 16 + u;
  const float bi = bias[ug], bff = bias[1024 + ug];
  const float bc = bias[2048 + ug], bo = bias[3072 + ug];
  float c_state = 0.f;

  #pragma unroll 1
  for (int t = 0; t < T_STEPS; ++t) {
    // ---- stage x rows (no h dependency; overlaps barrier slack) ----
    const unsigned short* xsrc = xbf + ((size_t)t * 64 + mg * 16) * 512;
    #pragma unroll
    for (int r = 0; r < 4; ++r) {
      int row = wave * 4 + r;
      g2l16(xsrc + (size_t)row * 512 + lane * 8, &Ax[row * 520]);
    }
    __syncthreads();
    f32x4 acc = {0.f, 0.f, 0.f, 0.f};
    #pragma unroll
    for (int kk = 0; kk < 16; ++kk) {
      short8 a = *(const short8*)&Ax[arow * 520 + kk * 32 + quad * 8];
      acc = __builtin_amdgcn_mfma_f32_16x16x32_bf16(a, wf[kk], acc, 0, 0, 0);
    }
    // ---- wait for h_{t-1} ----
    if (t > 0 && tid == 0) {
      while (__hip_atomic_load(&done2[(t - 1) * 16], __ATOMIC_ACQUIRE,
                               __HIP_MEMORY_SCOPE_AGENT) < NGRP)
        __builtin_amdgcn_s_sleep(1);
    }
    __syncthreads();
    __threadfence();   // acquire: invalidate caches before reading fresh h
    const unsigned short* hsrc =
        ((t & 1) ? hb0 : hb1) + (size_t)mg * 16 * 1024;
    #pragma unroll
    for (int r = 0; r < 4; ++r) {
      int row = wave * 4 + r;
      g2l16(hsrc + (size_t)row * 1024 + lane * 8, &Ah[row * 1032]);
      g2l16(hsrc + (size_t)row * 1024 + 512 + lane * 8, &Ah[row * 1032 + 512]);
    }
    __syncthreads();
    #pragma unroll
    for (int kk = 0; kk < 32; ++kk) {
      short8 a = *(const short8*)&Ah[arow * 1032 + kk * 32 + quad * 8];
      acc = __builtin_amdgcn_mfma_f32_16x16x32_bf16(a, wf[16 + kk], acc, 0, 0, 0);
    }
    // ---- gates to LDS (C/D layout: col=lane&15, row=quad*4+r) ----
    #pragma unroll
    for (int r = 0; r < 4; ++r)
      Gs[wave * 256 + (quad * 4 + r) * 16 + arow] = acc[r];
    __syncthreads();
    // ---- per-(m,u) gate math; 256 threads = 16 rows x 16 u ----
    float gi = Gs[tid] + bi;
    float gf = Gs[256 + tid] + bff;
    float gc = Gs[512 + tid] + bc;
    float go = Gs[768 + tid] + bo;
    float ig = 1.f / (1.f + __expf(-gi));
    float fg = 1.f / (1.f + __expf(-gf));
    float og = 1.f / (1.f + __expf(-go));
    float cb = tanhf(gc);
    c_state = fg * c_state + ig * cb;
    float h = og * tanhf(c_state);
    unsigned short* hdst = (t & 1) ? hb1 : hb0;
    hdst[(size_t)(mg * 16 + m) * 1024 + cg * 16 + u] = f2bf(h);
    if (t == T_STEPS - 1) {
      float* orow = out + (size_t)(mg * 16 + m) * 3072 + cg * 16 + u;
      orow[0] = h;
      orow[1024] = h;
      orow[2048] = c_state;
    }
    __threadfence();   // publish h stores (device scope)
    __syncthreads();
    if (tid == 0) {
      unsigned prev = __hip_atomic_fetch_add(&done1[(t * 16 + grp) * 16], 1u,
                                             __ATOMIC_ACQ_REL,
                                             __HIP_MEMORY_SCOPE_AGENT);
      if (prev == NGRP - 1)
        __hip_atomic_fetch_add(&done2[t * 16], 1u, __ATOMIC_ACQ_REL,
                               __HIP_MEMORY_SCOPE_AGENT);
    }
  }
}

extern "C" void kernel_launch(void* const* d_in, const int* in_sizes, int n_in,
                              void* d_out, int out_size, void* d_ws, size_t ws_size,
                              hipStream_t stream) {
  const float* x  = (const float*)d_in[0];
  const float* Wx = (const float*)d_in[1];
  const float* Wh = (const float*)d_in[2];
  const float* b  = (const float*)d_in[3];
  float* out = (float*)d_out;
  char* ws = (char*)d_ws;
  unsigned* done1 = (unsigned*)(ws + OFF_DONE1);
  unsigned* done2 = (unsigned*)(ws + OFF_DONE2);
  unsigned short* hb0 = (unsigned short*)(ws + OFF_HBUF0);
  unsigned short* hb1 = (unsigned short*)(ws + OFF_HBUF1);
  unsigned short* xbf = (unsigned short*)(ws + OFF_XBF);
  unsigned short* wp  = (unsigned short*)(ws + OFF_WPACK);

  // zero barrier counters + h double-buffer (ws is poisoned each call)
  hipMemsetAsync(d_ws, 0, MEMSET_BYTES, stream);
  k_xconv<<<8192, 256, 0, stream>>>(x, xbf);
  k_wpack<<<1536, 256, 0, stream>>>(Wx, Wh, wp);

  void* args[] = {&xbf, &wp, &b, &out, &done1, &done2, &hb0, &hb1};
  hipLaunchCooperativeKernel((void*)k_scan, dim3(256), dim3(256), args, 0, stream);
}